// Round 15
// baseline (373.458 us; speedup 1.0000x reference)
//
#include <hip/hip_runtime.h>

typedef __bf16 bf16x8 __attribute__((ext_vector_type(8)));
typedef __bf16 bf16x4 __attribute__((ext_vector_type(4)));
typedef float  f32x4  __attribute__((ext_vector_type(4)));

#define MFMA16 __builtin_amdgcn_mfma_f32_16x16x32_bf16

__device__ __forceinline__ float fsig(float x)  { return 1.f / (1.f + __expf(-x)); }
__device__ __forceinline__ float ftanh(float x) { return 1.f - 2.f / (__expf(2.f * x) + 1.f); }

// B=512, T=20, D=1024, H=1024, 4H=4096. Layer 0 of the LSTM is dead code.
// Rows sorted by dlen descending -> dead work contiguous -> block early-exit.
// DETERMINISM INVARIANT: every ws location read is written earlier in the SAME
// call (per-row liveness guard in lstm_step epilogue; hA/hB/cst zeroed in prep).
// LDS swizzle: granule slot s (8 elems) of row r holds global granule s^(r&7).
// Writes LINEAR in lane (conflict-free, measured 0); swizzle applied to the
// GLOBAL source column; reads XOR granule with (row&7) -> ~2-way max.
// gemm v4 (this round): 128(M)x256(N) tile, 512thr/8 waves, 32 MFMA per wave
// per K-iter (2x v3's per-barrier MFMA density; v3 was structure-bound at
// MfmaUtil 29%). Step v7: 32x128 tile, 2 blocks/CU (R14 best).

// ---- merged preprocessing ----
// blocks 0..2047: convert weights; block 2048: sort; blocks 2049..2304: zero
// hA/hB/cst (replaces 3 hipMemsetAsync launches).
__global__ __launch_bounds__(512) void prep(
    const float* __restrict__ Wih, const float* __restrict__ Whh,
    const float* __restrict__ W1,  const float* __restrict__ bih,
    const float* __restrict__ bhh, const int* __restrict__ dlen,
    __bf16* __restrict__ Wih1, __bf16* __restrict__ Whh1,
    __bf16* __restrict__ W1b,  float* __restrict__ bsum,
    int* __restrict__ perm, int* __restrict__ dl_s, int* __restrict__ n_act,
    float4* __restrict__ hA4, float4* __restrict__ hB4, float4* __restrict__ cst4)
{
    const int tid = threadIdx.x;
    if (blockIdx.x < 2048) {
        const size_t L1 = 4096UL * 1024UL;
        size_t i = (size_t)blockIdx.x * 512 + tid;       // 0 .. 1048575
        float4 a = *(const float4*)(Wih + L1 + i * 4);
        float4 b = *(const float4*)(Whh + L1 + i * 4);
        bf16x4 av = { (__bf16)a.x, (__bf16)a.y, (__bf16)a.z, (__bf16)a.w };
        bf16x4 bv = { (__bf16)b.x, (__bf16)b.y, (__bf16)b.z, (__bf16)b.w };
        *(bf16x4*)(Wih1 + i * 4) = av;
        *(bf16x4*)(Whh1 + i * 4) = bv;
        W1b[i] = (__bf16)W1[i];
        if (i < 4096) bsum[i] = bih[4096 + i] + bhh[4096 + i];
    } else if (blockIdx.x == 2048) {
        __shared__ int sdl[512];
        const int b = tid;
        const int dl = dlen[b];
        sdl[b] = dl;
        __syncthreads();
        int pos = 0;
        for (int j = 0; j < 512; ++j) {
            const int dj = sdl[j];
            pos += (dj > dl) || (dj == dl && j < b);
        }
        perm[pos] = b;
        dl_s[pos] = dl;
        if (b < 20) {
            int cnt = 0;
            for (int j = 0; j < 512; ++j) cnt += (sdl[j] > b);
            n_act[b] = cnt;       // #rows active at step t (n_act[0]==512)
        }
    } else {
        // zero hA (131072 f4), hB (131072 f4), cst (262144 f4)
        const int idx = (blockIdx.x - 2049) * 512 + tid;  // 0 .. 131071
        const float4 z = {0.f, 0.f, 0.f, 0.f};
        hA4[idx] = z;
        hB4[idx] = z;
        cst4[idx] = z;
        cst4[131072 + idx] = z;
    }
}

// ---- gather x in SORTED row order: xbf[t*512+sb] = [rel_emb | ent_emb] ----
__global__ __launch_bounds__(256) void gather_x(
    const int* __restrict__ ent, const int* __restrict__ rel,
    const float* __restrict__ ent_emb, const float* __restrict__ rel_emb,
    const int* __restrict__ perm, __bf16* __restrict__ xbf)
{
    int bid = blockIdx.x;              // sb*20 + t
    int sb = bid / 20, t = bid - sb * 20;
    int bo = perm[sb];
    int tid = threadIdx.x;
    int col = (tid & 127) * 4;
    const float* src = (tid < 128)
        ? (rel_emb + (size_t)rel[bo * 20 + t] * 512 + col)
        : (ent_emb + (size_t)ent[bo * 20 + t] * 512 + col);
    float4 v = *(const float4*)src;
    bf16x4 o = { (__bf16)v.x, (__bf16)v.y, (__bf16)v.z, (__bf16)v.w };
    int outcol = (tid < 128) ? col : (512 + col);
    *(bf16x4*)(xbf + (size_t)(t * 512 + sb) * 1024 + outcol) = o;
}

// ---- bf16 MFMA GEMM v4: 128x256 tile, 512thr/8 waves, dbuf, swizzled LDS ----
// Per wave: 64x64 output (acc[4][4]), 32 MFMA per K-iter (2x v3 density).
// Grid: x = colblock (n0, 256 wide) -> XCD = x%8 pins B slices; y = rowslab
// (m0, 128 rows; SKIP: dead if (m0&511) >= n_act[t]).
template<bool RELU, bool SKIP>
__global__ __launch_bounds__(512, 2) void gemm_bias(
    const __bf16* __restrict__ A, const __bf16* __restrict__ B,
    const float* __restrict__ bias, __bf16* __restrict__ C,
    int M, int N, int K, const int* __restrict__ nact)
{
    const int m0 = blockIdx.y * 128, n0 = blockIdx.x * 256;
    if (SKIP) {
        if ((m0 & 511) >= nact[m0 >> 9]) return;
    }
    __shared__ __bf16 As[2][128 * 64];     // 2 x 16 KB
    __shared__ __bf16 Bs[2][256 * 64];     // 2 x 32 KB
    const int tid = threadIdx.x;
    const int w = tid >> 6, lane = tid & 63;
    const int wr = (w >> 2) * 64;          // M half
    const int wc = (w & 3) * 64;           // N quarter
    const int srow = tid >> 3;                             // 0..63 staging row base
    const int scol = (((tid & 7) ^ (srow & 7)) << 3);      // swizzled source col
    const int wofs = srow * 64 + (tid & 7) * 8;            // LINEAR write (+j*64*64)

    f32x4 acc[4][4] = {};
    bf16x8 ar[2], br[4];

#pragma unroll
    for (int j = 0; j < 2; ++j)
        ar[j] = *(const bf16x8*)(A + (size_t)(m0 + j * 64 + srow) * K + scol);
#pragma unroll
    for (int j = 0; j < 4; ++j)
        br[j] = *(const bf16x8*)(B + (size_t)(n0 + j * 64 + srow) * K + scol);

    for (int k0 = 0, i = 0; k0 < K; k0 += 64, ++i) {
        const int cur = i & 1;
#pragma unroll
        for (int j = 0; j < 2; ++j)
            *(bf16x8*)&As[cur][wofs + j * 4096] = ar[j];
#pragma unroll
        for (int j = 0; j < 4; ++j)
            *(bf16x8*)&Bs[cur][wofs + j * 4096] = br[j];
        if (k0 + 64 < K) {
#pragma unroll
            for (int j = 0; j < 2; ++j)
                ar[j] = *(const bf16x8*)(A + (size_t)(m0 + j * 64 + srow) * K + k0 + 64 + scol);
#pragma unroll
            for (int j = 0; j < 4; ++j)
                br[j] = *(const bf16x8*)(B + (size_t)(n0 + j * 64 + srow) * K + k0 + 64 + scol);
        }
        __syncthreads();
#pragma unroll
        for (int ks = 0; ks < 2; ++ks) {
            const int ko = (((ks * 4 + (lane >> 4)) ^ (lane & 7)) << 3);
            bf16x8 af[4], bb[4];
#pragma unroll
            for (int ii = 0; ii < 4; ++ii)
                af[ii] = *(const bf16x8*)&As[cur][(wr + ii * 16 + (lane & 15)) * 64 + ko];
#pragma unroll
            for (int j = 0; j < 4; ++j)
                bb[j] = *(const bf16x8*)&Bs[cur][(wc + j * 16 + (lane & 15)) * 64 + ko];
#pragma unroll
            for (int ii = 0; ii < 4; ++ii)
#pragma unroll
                for (int j = 0; j < 4; ++j)
                    acc[ii][j] = MFMA16(af[ii], bb[j], acc[ii][j], 0, 0, 0);
        }
        __syncthreads();
    }
    const int rbase = m0 + wr + (lane >> 4) * 4;
    const int cbase = n0 + wc + (lane & 15);
#pragma unroll
    for (int j = 0; j < 4; ++j) {
        const int col = cbase + j * 16;
        const float bv = bias[col];
#pragma unroll
        for (int i = 0; i < 4; ++i)
#pragma unroll
            for (int r = 0; r < 4; ++r) {
                float v = acc[i][j][r] + bv;
                if (RELU) v = fmaxf(v, 0.f);
                C[(size_t)(rbase + i * 16 + r) * N + col] = (__bf16)v;
            }
    }
}

// ---- fused recurrent step v7 (R14-exact): 32x128 tile, 256thr, 2 blocks/CU ----
__global__ __launch_bounds__(256) void lstm_step(
    const __bf16* __restrict__ h_in, const __bf16* __restrict__ Whh,
    const __bf16* __restrict__ Xg, float* __restrict__ cst,
    __bf16* __restrict__ h_out, __bf16* __restrict__ sel,
    const int* __restrict__ dl_s, const int* __restrict__ perm,
    const int* __restrict__ n_act, int t)
{
    const int nt = n_act[t];
    const int m0 = blockIdx.y * 32;        // sorted batch-row block
    if (m0 >= nt) return;                  // whole slab dead at this step
    __shared__ __bf16 As[2][32 * 64];      // 2 x 4 KB
    __shared__ __bf16 Bs[2][128 * 64];     // 2 x 16 KB
    const int tid = threadIdx.x;
    const int w = tid >> 6, lane = tid & 63;
    const int j0 = blockIdx.x * 32;        // 32-channel block
    const int rh  = w >> 1;                // row half
    const int chq = w & 1;                 // channel half

    const int brow = tid >> 3;             // 0..31
    const int seg  = tid & 7;
    const int swc  = ((seg ^ (brow & 7)) << 3);
    const __bf16* gB = Whh + (size_t)(j0 + brow) * 1024 + swc;   // + g*1024*1024
    const __bf16* gA = h_in + (size_t)(m0 + brow) * 1024 + swc;

    f32x4 a0 = {0,0,0,0}, a1 = {0,0,0,0}, a2 = {0,0,0,0}, a3 = {0,0,0,0};
    bf16x8 rb0, rb1, rb2, rb3, ra;

    rb0 = *(const bf16x8*)(gB);
    rb1 = *(const bf16x8*)(gB + 1024UL * 1024);
    rb2 = *(const bf16x8*)(gB + 2048UL * 1024);
    rb3 = *(const bf16x8*)(gB + 3072UL * 1024);
    ra  = *(const bf16x8*)(gA);

    for (int k0 = 0, i = 0; k0 < 1024; k0 += 64, ++i) {
        const int cur = i & 1;
        *(bf16x8*)&Bs[cur][(0 * 32 + brow) * 64 + seg * 8] = rb0;
        *(bf16x8*)&Bs[cur][(1 * 32 + brow) * 64 + seg * 8] = rb1;
        *(bf16x8*)&Bs[cur][(2 * 32 + brow) * 64 + seg * 8] = rb2;
        *(bf16x8*)&Bs[cur][(3 * 32 + brow) * 64 + seg * 8] = rb3;
        *(bf16x8*)&As[cur][brow * 64 + seg * 8] = ra;
        if (k0 + 64 < 1024) {
            rb0 = *(const bf16x8*)(gB + k0 + 64);
            rb1 = *(const bf16x8*)(gB + 1024UL * 1024 + k0 + 64);
            rb2 = *(const bf16x8*)(gB + 2048UL * 1024 + k0 + 64);
            rb3 = *(const bf16x8*)(gB + 3072UL * 1024 + k0 + 64);
            ra  = *(const bf16x8*)(gA + k0 + 64);
        }
        __syncthreads();
#pragma unroll
        for (int ks = 0; ks < 2; ++ks) {
            const int ko = (((ks * 4 + (lane >> 4)) ^ (lane & 7)) << 3);
            bf16x8 av = *(const bf16x8*)&As[cur][(rh * 16 + (lane & 15)) * 64 + ko];
            bf16x8 b0 = *(const bf16x8*)&Bs[cur][(0 * 32 + chq * 16 + (lane & 15)) * 64 + ko];
            bf16x8 b1 = *(const bf16x8*)&Bs[cur][(1 * 32 + chq * 16 + (lane & 15)) * 64 + ko];
            bf16x8 b2 = *(const bf16x8*)&Bs[cur][(2 * 32 + chq * 16 + (lane & 15)) * 64 + ko];
            bf16x8 b3 = *(const bf16x8*)&Bs[cur][(3 * 32 + chq * 16 + (lane & 15)) * 64 + ko];
            a0 = MFMA16(av, b0, a0, 0, 0, 0);
            a1 = MFMA16(av, b1, a1, 0, 0, 0);
            a2 = MFMA16(av, b2, a2, 0, 0, 0);
            a3 = MFMA16(av, b3, a3, 0, 0, 0);
        }
    }
    const int ch  = j0 + chq * 16 + (lane & 15);
    const int rb_ = m0 + rh * 16 + (lane >> 4) * 4;
#pragma unroll
    for (int r = 0; r < 4; ++r) {
        const int b = rb_ + r;             // sorted row index
        if (b >= nt) continue;             // DEAD ROW: touch nothing (determinism)
        const __bf16* xg = Xg + (size_t)(t * 512 + b) * 4096 + ch;
        float gi = a0[r] + (float)xg[0];
        float gf = a1[r] + (float)xg[1024];
        float gg = a2[r] + (float)xg[2048];
        float go = a3[r] + (float)xg[3072];
        const size_t ix = (size_t)b * 1024 + ch;
        float cn = fsig(gf) * cst[ix] + fsig(gi) * ftanh(gg);
        cst[ix] = cn;
        float hv = fsig(go) * ftanh(cn);
        h_out[ix] = (__bf16)hv;
        if (dl_s[b] == t + 1)
            sel[(size_t)perm[b] * 1024 + ch] = (__bf16)hv;   // scatter to orig order
    }
}

// ---- final tiny layer: out[b,o] = relu(sum_k y1[b,k]*W2[o,k] + b2[o]) ----
__global__ __launch_bounds__(256) void mlp2(
    const __bf16* __restrict__ y1, const float* __restrict__ W2,
    const float* __restrict__ b2, float* __restrict__ out)
{
    int b = blockIdx.x, tid = threadIdx.x;
    float s0 = 0.f, s1 = 0.f;
    for (int k = tid; k < 1024; k += 256) {
        float v = (float)y1[(size_t)b * 1024 + k];
        s0 += v * W2[k];
        s1 += v * W2[1024 + k];
    }
#pragma unroll
    for (int o = 32; o > 0; o >>= 1) {
        s0 += __shfl_down(s0, o);
        s1 += __shfl_down(s1, o);
    }
    __shared__ float red[8];
    if ((tid & 63) == 0) { red[(tid >> 6) * 2] = s0; red[(tid >> 6) * 2 + 1] = s1; }
    __syncthreads();
    if (tid == 0) {
        float a0 = red[0] + red[2] + red[4] + red[6] + b2[0];
        float a1 = red[1] + red[3] + red[5] + red[7] + b2[1];
        out[b * 2 + 0] = fmaxf(a0, 0.f);
        out[b * 2 + 1] = fmaxf(a1, 0.f);
    }
}

extern "C" void kernel_launch(void* const* d_in, const int* in_sizes, int n_in,
                              void* d_out, int out_size, void* d_ws, size_t ws_size,
                              hipStream_t stream) {
    const int*   ent     = (const int*)d_in[0];
    const int*   rel     = (const int*)d_in[1];
    const int*   dlen    = (const int*)d_in[3];
    const float* ent_emb = (const float*)d_in[4];
    const float* rel_emb = (const float*)d_in[5];
    const float* Wih     = (const float*)d_in[6];
    const float* Whh     = (const float*)d_in[7];
    const float* bih     = (const float*)d_in[8];
    const float* bhh     = (const float*)d_in[9];
    const float* W1      = (const float*)d_in[10];
    const float* b1      = (const float*)d_in[11];
    const float* W2      = (const float*)d_in[12];
    const float* b2      = (const float*)d_in[13];
    float* out = (float*)d_out;

    char* ws = (char*)d_ws;
    size_t off = 0;
    auto alloc = [&](size_t bytes) -> void* {
        void* p = ws + off; off += (bytes + 255) & ~(size_t)255; return p;
    };
    __bf16* xbf   = (__bf16*)alloc(10240UL * 1024 * 2);  // [t*512+sb][1024]
    __bf16* Wih1  = (__bf16*)alloc(4096UL * 1024 * 2);
    __bf16* Whh1  = (__bf16*)alloc(4096UL * 1024 * 2);
    __bf16* W1b   = (__bf16*)alloc(1024UL * 1024 * 2);
    float*  bsum  = (float*) alloc(4096UL * 4);
    __bf16* Xg    = (__bf16*)alloc(10240UL * 4096 * 2);  // [t*512+sb][g*1024+ch]
    __bf16* hA    = (__bf16*)alloc(512UL * 1024 * 2);
    __bf16* hB    = (__bf16*)alloc(512UL * 1024 * 2);
    float*  cst   = (float*) alloc(512UL * 1024 * 4);
    __bf16* selb  = (__bf16*)alloc(512UL * 1024 * 2);    // ORIGINAL row order
    __bf16* y1b   = (__bf16*)alloc(512UL * 1024 * 2);
    int*    permb = (int*)   alloc(512 * 4);
    int*    dl_s  = (int*)   alloc(512 * 4);
    int*    n_act = (int*)   alloc(32 * 4);

    // merged convert + sort + state zeroing
    prep<<<dim3(2305), dim3(512), 0, stream>>>(
        Wih, Whh, W1, bih, bhh, dlen,
        Wih1, Whh1, W1b, bsum, permb, dl_s, n_act,
        (float4*)hA, (float4*)hB, (float4*)cst);
    gather_x<<<dim3(10240), dim3(256), 0, stream>>>(
        ent, rel, ent_emb, rel_emb, permb, xbf);
    // Xg = x @ W_ih[1]^T + (b_ih+b_hh); grid x=colblock (256 wide, XCD pin),
    // y=rowslab (skip axis; dead 128-row slabs exit).
    gemm_bias<false, true><<<dim3(16, 80), dim3(512), 0, stream>>>(
        xbf, Wih1, bsum, Xg, 10240, 4096, 1024, n_act);

    for (int t = 0; t < 20; ++t) {
        const __bf16* hi = (t & 1) ? hB : hA;
        __bf16*       ho = (t & 1) ? hA : hB;
        // grid: x = colblock (Whh slice -> XCD pin), y = rowblock (skip axis)
        lstm_step<<<dim3(32, 16), dim3(256), 0, stream>>>(
            hi, Whh1, Xg, cst, ho, selb, dl_s, permb, n_act, t);
    }

    // y1 = relu(sel @ W1^T + b1): M=512, N=1024 -> grid (4 colblocks, 4 rowslabs)
    gemm_bias<true, false><<<dim3(4, 4), dim3(512), 0, stream>>>(
        selb, W1b, b1, y1b, 512, 1024, 1024, nullptr);
    mlp2<<<dim3(512), dim3(256), 0, stream>>>(y1b, W2, b2, out);
}

// Round 16
// 358.094 us; speedup vs baseline: 1.0429x; 1.0429x over previous
//
#include <hip/hip_runtime.h>

typedef __bf16 bf16x8 __attribute__((ext_vector_type(8)));
typedef __bf16 bf16x4 __attribute__((ext_vector_type(4)));
typedef float  f32x4  __attribute__((ext_vector_type(4)));

#define MFMA16 __builtin_amdgcn_mfma_f32_16x16x32_bf16

__device__ __forceinline__ float fsig(float x)  { return 1.f / (1.f + __expf(-x)); }
__device__ __forceinline__ float ftanh(float x) { return 1.f - 2.f / (__expf(2.f * x) + 1.f); }

// B=512, T=20, D=1024, H=1024, 4H=4096. Layer 0 of the LSTM is dead code.
// Rows sorted by dlen descending -> dead work contiguous -> block early-exit.
// DETERMINISM INVARIANT: every ws location read is written earlier in the SAME
// call (per-row liveness guard in lstm_step epilogue; hA/hB/cst zeroed in prep).
// LDS swizzle: granule slot s (8 elems) of row r holds global granule s^(r&7).
// Writes LINEAR in lane (conflict-free, measured 0); swizzle applied to the
// GLOBAL source column; reads XOR granule with (row&7) -> ~2-way max.
// gemm v3 (R11-exact, proven 82us/29% MfmaUtil; R15's 128x256 v4 regressed:
// it added a 2nd barrier/iter and 96KB LDS dropped co-residency to 1 block/CU).
// Step v8: 64 rows x 64 gate-cols, 512 blocks -> B L2-traffic halved vs v7.

// ---- merged preprocessing ----
// blocks 0..2047: convert weights; block 2048: sort; blocks 2049..2304: zero
// hA/hB/cst (replaces 3 hipMemsetAsync launches).
__global__ __launch_bounds__(512) void prep(
    const float* __restrict__ Wih, const float* __restrict__ Whh,
    const float* __restrict__ W1,  const float* __restrict__ bih,
    const float* __restrict__ bhh, const int* __restrict__ dlen,
    __bf16* __restrict__ Wih1, __bf16* __restrict__ Whh1,
    __bf16* __restrict__ W1b,  float* __restrict__ bsum,
    int* __restrict__ perm, int* __restrict__ dl_s, int* __restrict__ n_act,
    float4* __restrict__ hA4, float4* __restrict__ hB4, float4* __restrict__ cst4)
{
    const int tid = threadIdx.x;
    if (blockIdx.x < 2048) {
        const size_t L1 = 4096UL * 1024UL;
        size_t i = (size_t)blockIdx.x * 512 + tid;       // 0 .. 1048575
        float4 a = *(const float4*)(Wih + L1 + i * 4);
        float4 b = *(const float4*)(Whh + L1 + i * 4);
        bf16x4 av = { (__bf16)a.x, (__bf16)a.y, (__bf16)a.z, (__bf16)a.w };
        bf16x4 bv = { (__bf16)b.x, (__bf16)b.y, (__bf16)b.z, (__bf16)b.w };
        *(bf16x4*)(Wih1 + i * 4) = av;
        *(bf16x4*)(Whh1 + i * 4) = bv;
        W1b[i] = (__bf16)W1[i];
        if (i < 4096) bsum[i] = bih[4096 + i] + bhh[4096 + i];
    } else if (blockIdx.x == 2048) {
        __shared__ int sdl[512];
        const int b = tid;
        const int dl = dlen[b];
        sdl[b] = dl;
        __syncthreads();
        int pos = 0;
        for (int j = 0; j < 512; ++j) {
            const int dj = sdl[j];
            pos += (dj > dl) || (dj == dl && j < b);
        }
        perm[pos] = b;
        dl_s[pos] = dl;
        if (b < 20) {
            int cnt = 0;
            for (int j = 0; j < 512; ++j) cnt += (sdl[j] > b);
            n_act[b] = cnt;       // #rows active at step t (n_act[0]==512)
        }
    } else {
        // zero hA (131072 f4), hB (131072 f4), cst (262144 f4)
        const int idx = (blockIdx.x - 2049) * 512 + tid;  // 0 .. 131071
        const float4 z = {0.f, 0.f, 0.f, 0.f};
        hA4[idx] = z;
        hB4[idx] = z;
        cst4[idx] = z;
        cst4[131072 + idx] = z;
    }
}

// ---- gather x in SORTED row order: xbf[t*512+sb] = [rel_emb | ent_emb] ----
__global__ __launch_bounds__(256) void gather_x(
    const int* __restrict__ ent, const int* __restrict__ rel,
    const float* __restrict__ ent_emb, const float* __restrict__ rel_emb,
    const int* __restrict__ perm, __bf16* __restrict__ xbf)
{
    int bid = blockIdx.x;              // sb*20 + t
    int sb = bid / 20, t = bid - sb * 20;
    int bo = perm[sb];
    int tid = threadIdx.x;
    int col = (tid & 127) * 4;
    const float* src = (tid < 128)
        ? (rel_emb + (size_t)rel[bo * 20 + t] * 512 + col)
        : (ent_emb + (size_t)ent[bo * 20 + t] * 512 + col);
    float4 v = *(const float4*)src;
    bf16x4 o = { (__bf16)v.x, (__bf16)v.y, (__bf16)v.z, (__bf16)v.w };
    int outcol = (tid < 128) ? col : (512 + col);
    *(bf16x4*)(xbf + (size_t)(t * 512 + sb) * 1024 + outcol) = o;
}

// ---- bf16 MFMA GEMM v3 (R11-exact): 128x128, dbuf, 1 barrier/iter ----
// Grid: x = colblock (n0), y = rowslab (m0) -> XCD = x%8 pins B slices.
// SKIP: block dead if (m0&511) >= n_act[t].
template<bool RELU, bool SKIP>
__global__ __launch_bounds__(256) void gemm_bias(
    const __bf16* __restrict__ A, const __bf16* __restrict__ B,
    const float* __restrict__ bias, __bf16* __restrict__ C,
    int M, int N, int K, const int* __restrict__ nact)
{
    const int m0 = blockIdx.y * 128, n0 = blockIdx.x * 128;
    if (SKIP) {
        if ((m0 & 511) >= nact[m0 >> 9]) return;
    }
    __shared__ __bf16 As[2][128 * 64];
    __shared__ __bf16 Bs[2][128 * 64];
    const int tid = threadIdx.x;
    const int w = tid >> 6, lane = tid & 63;
    const int wr = (w >> 1) * 64, wc = (w & 1) * 64;
    const int srow = w * 32 + (lane >> 3);                 // staging row (+j*8)
    const int scol = (((lane & 7) ^ (lane >> 3)) << 3);    // swizzled source col
    const int wofs = srow * 64 + (lane & 7) * 8;           // LINEAR write (+j*512)

    f32x4 acc[4][4] = {};
    bf16x8 ar[4], br[4];

#pragma unroll
    for (int j = 0; j < 4; ++j) {
        ar[j] = *(const bf16x8*)(A + (size_t)(m0 + srow + j * 8) * K + scol);
        br[j] = *(const bf16x8*)(B + (size_t)(n0 + srow + j * 8) * K + scol);
    }
    for (int k0 = 0, i = 0; k0 < K; k0 += 64, ++i) {
        const int cur = i & 1;
#pragma unroll
        for (int j = 0; j < 4; ++j) {
            *(bf16x8*)&As[cur][wofs + j * 512] = ar[j];
            *(bf16x8*)&Bs[cur][wofs + j * 512] = br[j];
        }
        if (k0 + 64 < K) {
#pragma unroll
            for (int j = 0; j < 4; ++j) {
                ar[j] = *(const bf16x8*)(A + (size_t)(m0 + srow + j * 8) * K + k0 + 64 + scol);
                br[j] = *(const bf16x8*)(B + (size_t)(n0 + srow + j * 8) * K + k0 + 64 + scol);
            }
        }
        __syncthreads();
#pragma unroll
        for (int ks = 0; ks < 2; ++ks) {
            const int ko = (((ks * 4 + (lane >> 4)) ^ (lane & 7)) << 3);
            bf16x8 af[4], bb[4];
#pragma unroll
            for (int ii = 0; ii < 4; ++ii)
                af[ii] = *(const bf16x8*)&As[cur][(wr + ii * 16 + (lane & 15)) * 64 + ko];
#pragma unroll
            for (int j = 0; j < 4; ++j)
                bb[j] = *(const bf16x8*)&Bs[cur][(wc + j * 16 + (lane & 15)) * 64 + ko];
#pragma unroll
            for (int ii = 0; ii < 4; ++ii)
#pragma unroll
                for (int j = 0; j < 4; ++j)
                    acc[ii][j] = MFMA16(af[ii], bb[j], acc[ii][j], 0, 0, 0);
        }
    }
    const int rbase = m0 + wr + (lane >> 4) * 4;
    const int cbase = n0 + wc + (lane & 15);
#pragma unroll
    for (int j = 0; j < 4; ++j) {
        const int col = cbase + j * 16;
        const float bv = bias[col];
#pragma unroll
        for (int i = 0; i < 4; ++i)
#pragma unroll
            for (int r = 0; r < 4; ++r) {
                float v = acc[i][j][r] + bv;
                if (RELU) v = fmaxf(v, 0.f);
                C[(size_t)(rbase + i * 16 + r) * N + col] = (__bf16)v;
            }
    }
}

// ---- fused recurrent step v8: 64 rows x 64 gate-cols, 256thr/4 waves ----
// Tile: 64 sorted rows x (4 gates x 16 ch). Grid: x = 64 colblocks (ch0=x*16;
// XCD = x%8 -> 8 x 128KB Whh slices = 1 MB/XCD), y = 8 rowblocks (skip axis).
// 512 blocks = 2 blocks/CU. Wave w: rows [w*16,+16), all 4 gates of its 16 ch
// (4 B-frags + 1 A-frag, 8 MFMA/iter — v7's proven per-wave shape). B-slice
// per block 128KB (half of v7) -> step L2 traffic 160->128 MB. LDS 32KB dbuf.
__global__ __launch_bounds__(256) void lstm_step(
    const __bf16* __restrict__ h_in, const __bf16* __restrict__ Whh,
    const __bf16* __restrict__ Xg, float* __restrict__ cst,
    __bf16* __restrict__ h_out, __bf16* __restrict__ sel,
    const int* __restrict__ dl_s, const int* __restrict__ perm,
    const int* __restrict__ n_act, int t)
{
    const int nt = n_act[t];
    const int m0 = blockIdx.y * 64;        // sorted batch-row block
    if (m0 >= nt) return;                  // whole slab dead at this step
    __shared__ __bf16 As[2][64 * 64];      // 2 x 8 KB
    __shared__ __bf16 Bs[2][64 * 64];      // 2 x 8 KB
    const int tid = threadIdx.x;
    const int w = tid >> 6, lane = tid & 63;
    const int ch0 = blockIdx.x * 16;       // 16-channel block

    // staging: thread -> row r (0..63), slots s0=tid&3 and s0+4; source
    // granule swizzled: slot s holds global granule s^(r&7).
    const int r_  = tid >> 2;              // 0..63
    const int s0_ = tid & 3, s1_ = s0_ + 4;
    const int g0 = ((s0_ ^ (r_ & 7)) << 3);   // elem offsets in k-chunk
    const int g1 = ((s1_ ^ (r_ & 7)) << 3);
    // B LDS row r = gate(r>>4)*16 + ch(r&15) <- Whh row (r>>4)*1024 + ch0 + (r&15)
    const __bf16* gBr = Whh + (size_t)((r_ >> 4) * 1024 + ch0 + (r_ & 15)) * 1024;
    const __bf16* gAr = h_in + (size_t)(m0 + r_) * 1024;

    f32x4 a0 = {0,0,0,0}, a1 = {0,0,0,0}, a2 = {0,0,0,0}, a3 = {0,0,0,0};
    bf16x8 rb0, rb1, ra0, ra1;

    rb0 = *(const bf16x8*)(gBr + g0);
    rb1 = *(const bf16x8*)(gBr + g1);
    ra0 = *(const bf16x8*)(gAr + g0);
    ra1 = *(const bf16x8*)(gAr + g1);

    for (int k0 = 0, i = 0; k0 < 1024; k0 += 64, ++i) {
        const int cur = i & 1;
        *(bf16x8*)&Bs[cur][r_ * 64 + s0_ * 8] = rb0;
        *(bf16x8*)&Bs[cur][r_ * 64 + s1_ * 8] = rb1;
        *(bf16x8*)&As[cur][r_ * 64 + s0_ * 8] = ra0;
        *(bf16x8*)&As[cur][r_ * 64 + s1_ * 8] = ra1;
        if (k0 + 64 < 1024) {
            rb0 = *(const bf16x8*)(gBr + g0 + k0 + 64);
            rb1 = *(const bf16x8*)(gBr + g1 + k0 + 64);
            ra0 = *(const bf16x8*)(gAr + g0 + k0 + 64);
            ra1 = *(const bf16x8*)(gAr + g1 + k0 + 64);
        }
        __syncthreads();
#pragma unroll
        for (int ks = 0; ks < 2; ++ks) {
            const int ko = (((ks * 4 + (lane >> 4)) ^ (lane & 7)) << 3);
            bf16x8 av = *(const bf16x8*)&As[cur][(w * 16 + (lane & 15)) * 64 + ko];
            bf16x8 b0 = *(const bf16x8*)&Bs[cur][(0 * 16 + (lane & 15)) * 64 + ko];
            bf16x8 b1 = *(const bf16x8*)&Bs[cur][(1 * 16 + (lane & 15)) * 64 + ko];
            bf16x8 b2 = *(const bf16x8*)&Bs[cur][(2 * 16 + (lane & 15)) * 64 + ko];
            bf16x8 b3 = *(const bf16x8*)&Bs[cur][(3 * 16 + (lane & 15)) * 64 + ko];
            a0 = MFMA16(av, b0, a0, 0, 0, 0);
            a1 = MFMA16(av, b1, a1, 0, 0, 0);
            a2 = MFMA16(av, b2, a2, 0, 0, 0);
            a3 = MFMA16(av, b3, a3, 0, 0, 0);
        }
    }
    // epilogue: lane owns 4 rows x 1 channel, gates = frags a0..a3 (i,f,g,o)
    const int ch  = ch0 + (lane & 15);
    const int rb_ = m0 + w * 16 + (lane >> 4) * 4;
#pragma unroll
    for (int r = 0; r < 4; ++r) {
        const int b = rb_ + r;             // sorted row index
        if (b >= nt) continue;             // DEAD ROW: touch nothing (determinism)
        const __bf16* xg = Xg + (size_t)(t * 512 + b) * 4096 + ch;
        float gi = a0[r] + (float)xg[0];
        float gf = a1[r] + (float)xg[1024];
        float gg = a2[r] + (float)xg[2048];
        float go = a3[r] + (float)xg[3072];
        const size_t ix = (size_t)b * 1024 + ch;
        float cn = fsig(gf) * cst[ix] + fsig(gi) * ftanh(gg);
        cst[ix] = cn;
        float hv = fsig(go) * ftanh(cn);
        h_out[ix] = (__bf16)hv;
        if (dl_s[b] == t + 1)
            sel[(size_t)perm[b] * 1024 + ch] = (__bf16)hv;   // scatter to orig order
    }
}

// ---- final tiny layer: out[b,o] = relu(sum_k y1[b,k]*W2[o,k] + b2[o]) ----
__global__ __launch_bounds__(256) void mlp2(
    const __bf16* __restrict__ y1, const float* __restrict__ W2,
    const float* __restrict__ b2, float* __restrict__ out)
{
    int b = blockIdx.x, tid = threadIdx.x;
    float s0 = 0.f, s1 = 0.f;
    for (int k = tid; k < 1024; k += 256) {
        float v = (float)y1[(size_t)b * 1024 + k];
        s0 += v * W2[k];
        s1 += v * W2[1024 + k];
    }
#pragma unroll
    for (int o = 32; o > 0; o >>= 1) {
        s0 += __shfl_down(s0, o);
        s1 += __shfl_down(s1, o);
    }
    __shared__ float red[8];
    if ((tid & 63) == 0) { red[(tid >> 6) * 2] = s0; red[(tid >> 6) * 2 + 1] = s1; }
    __syncthreads();
    if (tid == 0) {
        float a0 = red[0] + red[2] + red[4] + red[6] + b2[0];
        float a1 = red[1] + red[3] + red[5] + red[7] + b2[1];
        out[b * 2 + 0] = fmaxf(a0, 0.f);
        out[b * 2 + 1] = fmaxf(a1, 0.f);
    }
}

extern "C" void kernel_launch(void* const* d_in, const int* in_sizes, int n_in,
                              void* d_out, int out_size, void* d_ws, size_t ws_size,
                              hipStream_t stream) {
    const int*   ent     = (const int*)d_in[0];
    const int*   rel     = (const int*)d_in[1];
    const int*   dlen    = (const int*)d_in[3];
    const float* ent_emb = (const float*)d_in[4];
    const float* rel_emb = (const float*)d_in[5];
    const float* Wih     = (const float*)d_in[6];
    const float* Whh     = (const float*)d_in[7];
    const float* bih     = (const float*)d_in[8];
    const float* bhh     = (const float*)d_in[9];
    const float* W1      = (const float*)d_in[10];
    const float* b1      = (const float*)d_in[11];
    const float* W2      = (const float*)d_in[12];
    const float* b2      = (const float*)d_in[13];
    float* out = (float*)d_out;

    char* ws = (char*)d_ws;
    size_t off = 0;
    auto alloc = [&](size_t bytes) -> void* {
        void* p = ws + off; off += (bytes + 255) & ~(size_t)255; return p;
    };
    __bf16* xbf   = (__bf16*)alloc(10240UL * 1024 * 2);  // [t*512+sb][1024]
    __bf16* Wih1  = (__bf16*)alloc(4096UL * 1024 * 2);
    __bf16* Whh1  = (__bf16*)alloc(4096UL * 1024 * 2);
    __bf16* W1b   = (__bf16*)alloc(1024UL * 1024 * 2);
    float*  bsum  = (float*) alloc(4096UL * 4);
    __bf16* Xg    = (__bf16*)alloc(10240UL * 4096 * 2);  // [t*512+sb][g*1024+ch]
    __bf16* hA    = (__bf16*)alloc(512UL * 1024 * 2);
    __bf16* hB    = (__bf16*)alloc(512UL * 1024 * 2);
    float*  cst   = (float*) alloc(512UL * 1024 * 4);
    __bf16* selb  = (__bf16*)alloc(512UL * 1024 * 2);    // ORIGINAL row order
    __bf16* y1b   = (__bf16*)alloc(512UL * 1024 * 2);
    int*    permb = (int*)   alloc(512 * 4);
    int*    dl_s  = (int*)   alloc(512 * 4);
    int*    n_act = (int*)   alloc(32 * 4);

    // merged convert + sort + state zeroing
    prep<<<dim3(2305), dim3(512), 0, stream>>>(
        Wih, Whh, W1, bih, bhh, dlen,
        Wih1, Whh1, W1b, bsum, permb, dl_s, n_act,
        (float4*)hA, (float4*)hB, (float4*)cst);
    gather_x<<<dim3(10240), dim3(256), 0, stream>>>(
        ent, rel, ent_emb, rel_emb, permb, xbf);
    // Xg = x @ W_ih[1]^T + (b_ih+b_hh); grid x=colblock (XCD-pins B slices),
    // y=rowslab (skip axis; dead 128-row slabs exit).
    gemm_bias<false, true><<<dim3(32, 80), dim3(256), 0, stream>>>(
        xbf, Wih1, bsum, Xg, 10240, 4096, 1024, n_act);

    for (int t = 0; t < 20; ++t) {
        const __bf16* hi = (t & 1) ? hB : hA;
        __bf16*       ho = (t & 1) ? hA : hB;
        // grid: x = colblock (Whh slice -> XCD pin), y = rowblock (skip axis)
        lstm_step<<<dim3(64, 8), dim3(256), 0, stream>>>(
            hi, Whh1, Xg, cst, ho, selb, dl_s, permb, n_act, t);
    }

    // y1 = relu(sel @ W1^T + b1)
    gemm_bias<true, false><<<dim3(8, 4), dim3(256), 0, stream>>>(
        selb, W1b, b1, y1b, 512, 1024, 1024, nullptr);
    mlp2<<<dim3(512), dim3(256), 0, stream>>>(y1b, W2, b2, out);
}